// Round 9
// baseline (702.786 us; speedup 1.0000x reference)
//
#include <hip/hip_runtime.h>
#include <hip/hip_bf16.h>

// ---------------------------------------------------------------------------
// SelfAttention (B=2,S=2048,D=4096, NH=32,NKV=8,HD=128, NREP=4, non-causal)
// RoPE on K and V (reference quirk), NOT on Q.
// Round 9: gemm256 -> counted-vmcnt 8-phase schedule (T3+T4):
//   chunk-major LDS [2 khalf][4 kc][256][8] per operand (2-way bank = free),
//   4 phases x 16 MFMA per BK=64 tile, FIFO stage order Ah0,Ah1,Bh0,Bh1,
//   gates vmcnt(2)@ph0 / vmcnt(4)@ph2 (never drain except last tile).
// Attn/rope/cvt unchanged from round 8.
// ---------------------------------------------------------------------------

typedef short bf16x8 __attribute__((ext_vector_type(8)));
typedef float f32x4 __attribute__((ext_vector_type(4)));

__device__ __forceinline__ void load16(const void* g, void* l) {
  __builtin_amdgcn_global_load_lds(
      (const __attribute__((address_space(1))) void*)g,
      (__attribute__((address_space(3))) void*)l, 16, 0, 0);
}

__device__ __forceinline__ f32x4 mfma16(bf16x8 a, bf16x8 b, f32x4 c) {
  return __builtin_amdgcn_mfma_f32_16x16x32_bf16(a, b, c, 0, 0, 0);
}

__device__ __forceinline__ unsigned short f2b(float f) {
  union { float f; unsigned int u; } v; v.f = f;
  unsigned int u = v.u;
  return (unsigned short)((u + 0x7fffu + ((u >> 16) & 1u)) >> 16);
}
__device__ __forceinline__ float b2f(unsigned short u) {
  union { unsigned int u; float f; } v; v.u = ((unsigned int)u) << 16;
  return v.f;
}
__device__ __forceinline__ unsigned short f2b_fast(float f) {
  __hip_bfloat16 h = __float2bfloat16(f);
  return *reinterpret_cast<unsigned short*>(&h);
}

#define QSCALE (0.08838834764831845f * 1.4426950408889634f)

// ---------------------------------------------------------------------------
__global__ __launch_bounds__(256) void cvt_f32_bf16(
    const float* __restrict__ in, unsigned short* __restrict__ out, int n4) {
  int idx = blockIdx.x * 256 + threadIdx.x;
  int stride = gridDim.x * 256;
  for (int i = idx; i < n4; i += stride) {
    float4 v = reinterpret_cast<const float4*>(in)[i];
    ushort4 o;
    o.x = f2b(v.x); o.y = f2b(v.y); o.z = f2b(v.z); o.w = f2b(v.w);
    reinterpret_cast<ushort4*>(out)[i] = o;
  }
}

// ---------------------------------------------------------------------------
// 256x256 tile, BK=64, 8 waves (2Mx4N), per-wave 128x64 output.
// LDS per buffer: A = [h2][kc4][256 rows][8 hw] (32KB), B same (32KB);
// 2 buffers = 131072 B. All ds_read_b128 land 2 lanes/bank (free).
// Phases (16 MFMA each), FIFO staging -> counted gates:
//   ph0: gate vmcnt(2); read A(k0) x8 + B01(k0); stage Ah0(t+1); MFMA k0 n01
//   ph1:               read B23(k0);            stage Ah1(t+1); MFMA k0 n23
//   ph2: gate vmcnt(4); read A(k1) x8 + B01(k1); stage Bh0(t+1); MFMA k1 n01
//   ph3:               read B23(k1);            stage Bh1(t+1); MFMA k1 n23
template <typename OutT>
__global__ __launch_bounds__(512, 2) void gemm256(
    const unsigned short* __restrict__ A, const unsigned short* __restrict__ Bw,
    OutT* __restrict__ C, int M, int N, int K, int sbl) {
  extern __shared__ char smem[];  // 131072
  const int tid = threadIdx.x;
  const int lane = tid & 63;
  const int w = tid >> 6;
  const int lr = lane & 15, lg = lane >> 4;
  const int wr = w >> 2, wc = w & 3;

  const int nbn = N >> 8;
  const int bid = blockIdx.x, nwg = gridDim.x;
  const int swz = (bid & 7) * (nwg >> 3) + (bid >> 3);  // nwg % 8 == 0
  const int bm = swz / nbn, bn = swz % nbn;

  const unsigned short* Ag = A + (size_t)bm * 256 * K;
  const unsigned short* Bg = Bw + (size_t)bn * 256 * K;

  // staging: per half-block 1024 chunks of 16B; thread does c0=tid, c1=tid+512
  // chunk c: row = c&255, kc = c>>8 ; src hw = row*K + t*64 + h*32 + kc*8
  const int row0 = tid & 255, kc0 = tid >> 8;          // c0
  const int row1 = tid & 255, kc1 = (tid >> 8) + 2;    // c1 = tid+512
  const int sdst = (tid & ~63) * 16;                   // wave-uniform base

  f32x4 acc[8][4];
#pragma unroll
  for (int m = 0; m < 8; ++m)
#pragma unroll
    for (int n = 0; n < 4; ++n) acc[m][n] = (f32x4){0.f, 0.f, 0.f, 0.f};

  // STAGE one half (h) of one operand (base: 0 for A, 32768 for B) of tile tt
#define STAGE_H(gptr, obase, hh, tt)                                          \
  {                                                                           \
    char* d = smem + (((tt)&1) * 65536) + (obase) + (hh)*16384;               \
    load16(gptr + (size_t)row0 * K + ((tt) << 6) + (hh)*32 + kc0 * 8,         \
           d + sdst);                                                         \
    load16(gptr + (size_t)row1 * K + ((tt) << 6) + (hh)*32 + kc1 * 8,         \
           d + sdst + 8192);                                                  \
  }

  // prologue: tile 0 in FIFO order Ah0, Ah1, Bh0, Bh1 (8 loads/thread)
  STAGE_H(Ag, 0, 0, 0);
  STAGE_H(Ag, 0, 1, 0);
  STAGE_H(Bg, 32768, 0, 0);
  STAGE_H(Bg, 32768, 1, 0);

  const int NT = K >> 6;
  const int aRowB = (wr * 128 + lr) * 16 + lg * 4096;  // + h*16384 + mf*256
  const int bRowB = (wc * 64 + lr) * 16 + lg * 4096;   // + h*16384 + nf*256

  bf16x8 aR[8], bR[4];

  for (int t = 0; t < NT; ++t) {
    const char* bufA = smem + (t & 1) * 65536;
    const char* bufB = bufA + 32768;
    const bool more = (t + 1) < NT;

    // ================= ph0 (k-half 0) =================
    asm volatile("s_waitcnt vmcnt(2)" ::: "memory");  // Ah0,Ah1,Bh0 landed
    __builtin_amdgcn_s_barrier();
#pragma unroll
    for (int mf = 0; mf < 8; ++mf)
      aR[mf] = *(const bf16x8*)(bufA + aRowB + mf * 256);
#pragma unroll
    for (int nf = 0; nf < 2; ++nf)
      bR[nf] = *(const bf16x8*)(bufB + bRowB + nf * 256);
    if (more) STAGE_H(Ag, 0, 0, t + 1);
    __builtin_amdgcn_s_barrier();
    asm volatile("s_waitcnt lgkmcnt(0)" ::: "memory");
    __builtin_amdgcn_sched_barrier(0);
    __builtin_amdgcn_s_setprio(1);
#pragma unroll
    for (int mf = 0; mf < 8; ++mf)
#pragma unroll
      for (int nf = 0; nf < 2; ++nf)
        acc[mf][nf] = mfma16(aR[mf], bR[nf], acc[mf][nf]);
    __builtin_amdgcn_s_setprio(0);
    __builtin_amdgcn_s_barrier();

    // ================= ph1 (k-half 0, n23) =================
#pragma unroll
    for (int nf = 2; nf < 4; ++nf)
      bR[nf] = *(const bf16x8*)(bufB + bRowB + nf * 256);
    if (more) STAGE_H(Ag, 0, 1, t + 1);
    __builtin_amdgcn_s_barrier();
    asm volatile("s_waitcnt lgkmcnt(0)" ::: "memory");
    __builtin_amdgcn_sched_barrier(0);
    __builtin_amdgcn_s_setprio(1);
#pragma unroll
    for (int mf = 0; mf < 8; ++mf)
#pragma unroll
      for (int nf = 2; nf < 4; ++nf)
        acc[mf][nf] = mfma16(aR[mf], bR[nf], acc[mf][nf]);
    __builtin_amdgcn_s_setprio(0);
    __builtin_amdgcn_s_barrier();

    // ================= ph2 (k-half 1) =================
    if (more) { asm volatile("s_waitcnt vmcnt(4)" ::: "memory"); }
    else      { asm volatile("s_waitcnt vmcnt(0)" ::: "memory"); }
    __builtin_amdgcn_s_barrier();
#pragma unroll
    for (int mf = 0; mf < 8; ++mf)
      aR[mf] = *(const bf16x8*)(bufA + 16384 + aRowB + mf * 256);
#pragma unroll
    for (int nf = 0; nf < 2; ++nf)
      bR[nf] = *(const bf16x8*)(bufB + 16384 + bRowB + nf * 256);
    if (more) STAGE_H(Bg, 32768, 0, t + 1);
    __builtin_amdgcn_s_barrier();
    asm volatile("s_waitcnt lgkmcnt(0)" ::: "memory");
    __builtin_amdgcn_sched_barrier(0);
    __builtin_amdgcn_s_setprio(1);
#pragma unroll
    for (int mf = 0; mf < 8; ++mf)
#pragma unroll
      for (int nf = 0; nf < 2; ++nf)
        acc[mf][nf] = mfma16(aR[mf], bR[nf], acc[mf][nf]);
    __builtin_amdgcn_s_setprio(0);
    __builtin_amdgcn_s_barrier();

    // ================= ph3 (k-half 1, n23) =================
#pragma unroll
    for (int nf = 2; nf < 4; ++nf)
      bR[nf] = *(const bf16x8*)(bufB + 16384 + bRowB + nf * 256);
    if (more) STAGE_H(Bg, 32768, 1, t + 1);
    __builtin_amdgcn_s_barrier();
    asm volatile("s_waitcnt lgkmcnt(0)" ::: "memory");
    __builtin_amdgcn_sched_barrier(0);
    __builtin_amdgcn_s_setprio(1);
#pragma unroll
    for (int mf = 0; mf < 8; ++mf)
#pragma unroll
      for (int nf = 2; nf < 4; ++nf)
        acc[mf][nf] = mfma16(aR[mf], bR[nf], acc[mf][nf]);
    __builtin_amdgcn_s_setprio(0);
    __builtin_amdgcn_s_barrier();
  }
#undef STAGE_H

  const float cscale = (bn < sbl) ? QSCALE : 1.0f;
#pragma unroll
  for (int mf = 0; mf < 8; ++mf)
#pragma unroll
    for (int nf = 0; nf < 4; ++nf)
#pragma unroll
      for (int r = 0; r < 4; ++r) {
        int rowc = bm * 256 + wr * 128 + mf * 16 + lg * 4 + r;
        int colc = bn * 256 + wc * 64 + nf * 16 + lr;
        float v = acc[mf][nf][r] * cscale;
        if constexpr (sizeof(OutT) == 2)
          C[(size_t)rowc * N + colc] = (OutT)f2b(v);
        else
          C[(size_t)rowc * N + colc] = v;
      }
}

// ---------------------------------------------------------------------------
// RoPE on K and V read from fused XQKV (row stride 6144; K at col 4096+,
// V at col 5120+). K -> Kr (b,kv,s,d); V -> Vt (b,kv,d,s) transposed.
__global__ __launch_bounds__(256) void rope_kv(
    const unsigned short* __restrict__ XQKV,
    const float* __restrict__ fc, const float* __restrict__ fs,
    unsigned short* __restrict__ Kr, unsigned short* __restrict__ Vt) {
  __shared__ unsigned short Vl[128][66];
  const int t = threadIdx.x;
  const int bid = blockIdx.x;  // bkv*32 + stile
  const int stile = bid & 31, bkv = bid >> 5;
  const int b = bkv >> 3, kvh = bkv & 7;
  const int s0 = stile * 64;
  const int l = t & 63;
  const int jrow = t >> 6;

  for (int j = 0; j < 16; ++j) {
    int s = s0 + j * 4 + jrow;
    ushort2 v = *(const ushort2*)(XQKV + (size_t)(b * 2048 + s) * 6144 + 4096 +
                                  kvh * 128 + 2 * l);
    float c = fc[s * 64 + l], sn = fs[s * 64 + l];
    float xr = b2f(v.x), xi = b2f(v.y);
    ushort2 o;
    o.x = f2b(xr * c - xi * sn);
    o.y = f2b(xr * sn + xi * c);
    *(ushort2*)(Kr + ((size_t)bkv * 2048 + s) * 128 + 2 * l) = o;
  }
  for (int j = 0; j < 16; ++j) {
    int ss = j * 4 + jrow;
    int s = s0 + ss;
    ushort2 v = *(const ushort2*)(XQKV + (size_t)(b * 2048 + s) * 6144 + 5120 +
                                  kvh * 128 + 2 * l);
    float c = fc[s * 64 + l], sn = fs[s * 64 + l];
    float xr = b2f(v.x), xi = b2f(v.y);
    Vl[2 * l][ss] = f2b(xr * c - xi * sn);
    Vl[2 * l + 1][ss] = f2b(xr * sn + xi * c);
  }
  __syncthreads();
  const int d = t >> 1, half = t & 1;
  unsigned short* vdst = Vt + ((size_t)bkv * 128 + d) * 2048 + s0 + half * 32;
#pragma unroll
  for (int e = 0; e < 32; e += 4) {
    ushort4 pk;
    pk.x = Vl[d][half * 32 + e];
    pk.y = Vl[d][half * 32 + e + 1];
    pk.z = Vl[d][half * 32 + e + 2];
    pk.w = Vl[d][half * 32 + e + 3];
    *(ushort4*)(vdst + e) = pk;
  }
}

// ---------------------------------------------------------------------------
// Flash attention (round-6 structure; XQ row stride 6144; native bf16 cvt).
__global__ __launch_bounds__(256, 2) void attn_fwd(
    const unsigned short* __restrict__ XQ, const unsigned short* __restrict__ Kr,
    const unsigned short* __restrict__ Vt, unsigned short* __restrict__ AO) {
  extern __shared__ char smem[];  // 81920
  char* Ksm = smem;                                      // [2][16384]
  char* Vsm = smem + 32768;                              // [2][16384]
  unsigned short* Ps = (unsigned short*)(smem + 65536);  // [4][8][32][8]
  const int t = threadIdx.x;
  const int lane = t & 63, w = t >> 6;
  const int lr = lane & 15, lg = lane >> 4;

  const int bid = blockIdx.x;
  const int nwg = gridDim.x;  // 1024
  const int swz = (bid & 7) * (nwg >> 3) + (bid >> 3);
  const int qt = swz & 15;
  const int bh = swz >> 4;
  const int b = bh >> 5, h = bh & 31;
  const int bkv = b * 8 + (h >> 2);

  bf16x8 qf[2][4];
#pragma unroll
  for (int q2 = 0; q2 < 2; ++q2) {
    const unsigned short* qp =
        XQ + ((size_t)(b * 2048 + qt * 128 + w * 32 + q2 * 16 + lr)) * 6144 +
        h * 128 + lg * 8;
#pragma unroll
    for (int dc = 0; dc < 4; ++dc) qf[q2][dc] = *(const bf16x8*)(qp + dc * 32);
  }

  f32x4 acc[2][8];
#pragma unroll
  for (int q2 = 0; q2 < 2; ++q2)
#pragma unroll
    for (int i = 0; i < 8; ++i) acc[q2][i] = (f32x4){0.f, 0.f, 0.f, 0.f};
  float l_[2][4] = {{0.f, 0.f, 0.f, 0.f}, {0.f, 0.f, 0.f, 0.f}};

  const unsigned short* Kbase = Kr + (size_t)bkv * 2048 * 128;
  const unsigned short* Vbase = Vt + (size_t)bkv * 128 * 2048;

  int kK[4], dC[4], vD[4], vKc[4], dstb[4];
#pragma unroll
  for (int j = 0; j < 4; ++j) {
    const int c = t + j * 256;
    kK[j] = c & 63;  dC[j] = c >> 6;
    vD[j] = c & 127; vKc[j] = c >> 7;
    dstb[j] = (c & ~63) * 16;
  }

#define STAGE_KV(bufi, kt)                                                    \
  {                                                                           \
    char* kd = Ksm + (bufi)*16384;                                            \
    char* vd = Vsm + (bufi)*16384;                                            \
    _Pragma("unroll") for (int j = 0; j < 4; ++j) {                           \
      load16(Kbase + (size_t)((kt)*64 + kK[j]) * 128 + dC[j] * 8, kd + dstb[j]); \
      load16(Vbase + (size_t)vD[j] * 2048 + (kt)*64 + vKc[j] * 8, vd + dstb[j]); \
    }                                                                         \
  }

  STAGE_KV(0, 0);
  asm volatile("s_waitcnt vmcnt(0)" ::: "memory");
  __builtin_amdgcn_s_barrier();

  unsigned short* Pw = Ps + w * 2048;              // [8 kc][32 q][8]
  const int pbase = (lr >> 3) * 256 + (lr & 7);    // halfword offset

  for (int kt = 0; kt < 32; ++kt) {
    const int cur = kt & 1;
    if (kt < 31) STAGE_KV(cur ^ 1, kt + 1);

    const char* Kc = Ksm + cur * 16384;
    const char* Vc = Vsm + cur * 16384;

#pragma unroll
    for (int nf = 0; nf < 4; ++nf) {
      f32x4 s0 = (f32x4){0.f, 0.f, 0.f, 0.f};
      f32x4 s1 = (f32x4){0.f, 0.f, 0.f, 0.f};
#pragma unroll
      for (int dc = 0; dc < 4; ++dc) {
        bf16x8 kf =
            *(const bf16x8*)(Kc + ((dc * 4 + lg) * 64 + nf * 16 + lr) * 16);
        s0 = mfma16(qf[0][dc], kf, s0);
        s1 = mfma16(qf[1][dc], kf, s1);
      }
      const int pb = pbase + nf * 512;  // kc = nf*2 + (lr>>3)
#pragma unroll
      for (int r = 0; r < 4; ++r) {
        float p0 = __builtin_amdgcn_exp2f(s0[r]);
        float p1 = __builtin_amdgcn_exp2f(s1[r]);
        l_[0][r] += p0;
        l_[1][r] += p1;
        Pw[pb + (lg * 4 + r) * 8] = f2b_fast(p0);
        Pw[pb + (16 + lg * 4 + r) * 8] = f2b_fast(p1);
      }
    }

#pragma unroll
    for (int ks = 0; ks < 2; ++ks) {
      bf16x8 pf0 = *(const bf16x8*)(Pw + (ks * 4 + lg) * 256 + lr * 8);
      bf16x8 pf1 = *(const bf16x8*)(Pw + (ks * 4 + lg) * 256 + (16 + lr) * 8);
#pragma unroll
      for (int dt = 0; dt < 8; ++dt) {
        bf16x8 vf =
            *(const bf16x8*)(Vc + ((ks * 4 + lg) * 128 + dt * 16 + lr) * 16);
        acc[0][dt] = mfma16(pf0, vf, acc[0][dt]);
        acc[1][dt] = mfma16(pf1, vf, acc[1][dt]);
      }
    }

    asm volatile("s_waitcnt vmcnt(0)" ::: "memory");
    __builtin_amdgcn_s_barrier();
  }
#undef STAGE_KV

#pragma unroll
  for (int q2 = 0; q2 < 2; ++q2)
#pragma unroll
    for (int r = 0; r < 4; ++r) {
#pragma unroll
      for (int o = 1; o < 16; o <<= 1) l_[q2][r] += __shfl_xor(l_[q2][r], o);
    }

#pragma unroll
  for (int q2 = 0; q2 < 2; ++q2)
#pragma unroll
    for (int r = 0; r < 4; ++r) {
      float inv = 1.f / l_[q2][r];
      size_t rowb =
          ((size_t)(b * 2048 + qt * 128 + w * 32 + q2 * 16 + lg * 4 + r)) * 4096 +
          h * 128;
#pragma unroll
      for (int dt = 0; dt < 8; ++dt)
        AO[rowb + dt * 16 + lr] = f2b_fast(acc[q2][dt][r] * inv);
    }
}

// ---------------------------------------------------------------------------
extern "C" void kernel_launch(void* const* d_in, const int* in_sizes, int n_in,
                              void* d_out, int out_size, void* d_ws, size_t ws_size,
                              hipStream_t stream) {
  const float* x  = (const float*)d_in[0];
  const float* fc = (const float*)d_in[2];
  const float* fs = (const float*)d_in[3];
  const float* wq = (const float*)d_in[4];
  const float* wk = (const float*)d_in[5];
  const float* wv = (const float*)d_in[6];
  const float* wo = (const float*)d_in[7];

  const size_t MB = 1024ull * 1024ull;
  char* ws = (char*)d_ws;
  unsigned short* Xb   = (unsigned short*)(ws);           // 32MB, dead after QKV gemm
  unsigned short* Wsc  = (unsigned short*)(ws + 32 * MB); // 48MB (wq|wk|wv), later wo
  unsigned short* Kr   = (unsigned short*)(ws);           // [0,8) reuse Xb
  unsigned short* Vt   = (unsigned short*)(ws + 8 * MB);  // [8,16)
  unsigned short* AO   = (unsigned short*)(ws + 80 * MB); // 32MB
  unsigned short* XQKV = (unsigned short*)d_out;          // 48MB of 64MB d_out

  (void)hipFuncSetAttribute((const void*)gemm256<unsigned short>,
                            hipFuncAttributeMaxDynamicSharedMemorySize, 131072);
  (void)hipFuncSetAttribute((const void*)gemm256<float>,
                            hipFuncAttributeMaxDynamicSharedMemorySize, 131072);
  (void)hipFuncSetAttribute((const void*)attn_fwd,
                            hipFuncAttributeMaxDynamicSharedMemorySize, 81920);

  dim3 blk(256);
  dim3 blk512(512);
  cvt_f32_bf16<<<2048, blk, 0, stream>>>(x, Xb, (2 * 2048 * 4096) / 4);
  cvt_f32_bf16<<<2048, blk, 0, stream>>>(wq, Wsc, (4096 * 4096) / 4);
  cvt_f32_bf16<<<2048, blk, 0, stream>>>(wk, Wsc + 4096 * 4096, (1024 * 4096) / 4);
  cvt_f32_bf16<<<2048, blk, 0, stream>>>(wv, Wsc + 5120 * 4096, (1024 * 4096) / 4);
  gemm256<unsigned short><<<384, blk512, 131072, stream>>>(
      Xb, Wsc, XQKV, 4096, 6144, 4096, /*sbl=*/16);
  rope_kv<<<512, blk, 0, stream>>>(XQKV, fc, fs, Kr, Vt);
  attn_fwd<<<1024, blk, 81920, stream>>>(XQKV, Kr, Vt, AO);
  cvt_f32_bf16<<<2048, blk, 0, stream>>>(wo, Wsc, (4096 * 4096) / 4);
  gemm256<float><<<256, blk512, 131072, stream>>>(
      AO, Wsc, (float*)d_out, 4096, 4096, 4096, /*sbl=*/0);
}

// Round 10
// 564.717 us; speedup vs baseline: 1.2445x; 1.2445x over previous
//
#include <hip/hip_runtime.h>
#include <hip/hip_bf16.h>

// ---------------------------------------------------------------------------
// SelfAttention (B=2,S=2048,D=4096, NH=32,NKV=8,HD=128, NREP=4, non-causal)
// RoPE on K and V (reference quirk), NOT on Q.
// Round 10: gemm256 reverted to the round-8 kernel (best measured).
//   attn: 64 q-rows per wave (qtile=256, grid 512, 2 blocks/CU exact),
//   KVBLK=32, r5-verified chunk-major LDS, K/V frags reused x4 across q.
// ---------------------------------------------------------------------------

typedef short bf16x8 __attribute__((ext_vector_type(8)));
typedef float f32x4 __attribute__((ext_vector_type(4)));

__device__ __forceinline__ void load16(const void* g, void* l) {
  __builtin_amdgcn_global_load_lds(
      (const __attribute__((address_space(1))) void*)g,
      (__attribute__((address_space(3))) void*)l, 16, 0, 0);
}

__device__ __forceinline__ f32x4 mfma16(bf16x8 a, bf16x8 b, f32x4 c) {
  return __builtin_amdgcn_mfma_f32_16x16x32_bf16(a, b, c, 0, 0, 0);
}

__device__ __forceinline__ unsigned short f2b(float f) {
  union { float f; unsigned int u; } v; v.f = f;
  unsigned int u = v.u;
  return (unsigned short)((u + 0x7fffu + ((u >> 16) & 1u)) >> 16);
}
__device__ __forceinline__ float b2f(unsigned short u) {
  union { unsigned int u; float f; } v; v.u = ((unsigned int)u) << 16;
  return v.f;
}
__device__ __forceinline__ unsigned short f2b_fast(float f) {
  __hip_bfloat16 h = __float2bfloat16(f);
  return *reinterpret_cast<unsigned short*>(&h);
}

#define QSCALE (0.08838834764831845f * 1.4426950408889634f)

// ---------------------------------------------------------------------------
__global__ __launch_bounds__(256) void cvt_f32_bf16(
    const float* __restrict__ in, unsigned short* __restrict__ out, int n4) {
  int idx = blockIdx.x * 256 + threadIdx.x;
  int stride = gridDim.x * 256;
  for (int i = idx; i < n4; i += stride) {
    float4 v = reinterpret_cast<const float4*>(in)[i];
    ushort4 o;
    o.x = f2b(v.x); o.y = f2b(v.y); o.z = f2b(v.z); o.w = f2b(v.w);
    reinterpret_cast<ushort4*>(out)[i] = o;
  }
}

// ---------------------------------------------------------------------------
// Round-8 gemm256 (verbatim): 256x256 tile, BK=64, 8 waves, 4 phases/tile,
// row-XOR-8 swizzle, vmcnt(0) gate per tile.
template <typename OutT>
__global__ __launch_bounds__(512, 2) void gemm256(
    const unsigned short* __restrict__ A, const unsigned short* __restrict__ Bw,
    OutT* __restrict__ C, int M, int N, int K, int sbl) {
  extern __shared__ char smem[];  // 131072 bytes
  const int tid = threadIdx.x;
  const int lane = tid & 63;
  const int w = tid >> 6;
  const int lr = lane & 15, lg = lane >> 4;
  const int wr = w >> 2, wc = w & 3;

  const int nbn = N >> 8;
  const int bid = blockIdx.x, nwg = gridDim.x;
  const int swz = (bid & 7) * (nwg >> 3) + (bid >> 3);  // nwg % 8 == 0
  const int bm = swz / nbn, bn = swz % nbn;

  const unsigned short* Ag = A + (size_t)bm * 256 * K;
  const unsigned short* Bg = Bw + (size_t)bn * 256 * K;

  int srow[4], skhw[4], sdst[4];
#pragma unroll
  for (int j = 0; j < 4; ++j) {
    const int c = tid + j * 512;
    srow[j] = c >> 3;
    skhw[j] = ((c & 7) ^ ((c >> 3) & 7)) << 3;
    sdst[j] = ((tid & ~63) << 4) + j * 8192;
  }

  f32x4 acc[8][4];
#pragma unroll
  for (int m = 0; m < 8; ++m)
#pragma unroll
    for (int n = 0; n < 4; ++n) acc[m][n] = (f32x4){0.f, 0.f, 0.f, 0.f};

#define STAGEA4(tt)                                                           \
  {                                                                           \
    char* d = smem + (((tt)&1) * 65536);                                      \
    _Pragma("unroll") for (int j = 0; j < 4; ++j)                             \
        load16(Ag + (size_t)srow[j] * K + ((tt) << 6) + skhw[j], d + sdst[j]);\
  }
#define STAGEB4(tt)                                                           \
  {                                                                           \
    char* d = smem + (((tt)&1) * 65536) + 32768;                              \
    _Pragma("unroll") for (int j = 0; j < 4; ++j)                             \
        load16(Bg + (size_t)srow[j] * K + ((tt) << 6) + skhw[j], d + sdst[j]);\
  }

  STAGEB4(0);
  STAGEA4(0);

  const int NT = K >> 6;
  const int rx = (lr & 7) << 4;
  const int aRow0 = (wr * 128 + lr) * 128;
  const int bRow0 = (wc * 64 + lr) * 128;
  const int col0 = (lg * 16) ^ rx;
  const int col1 = (64 + lg * 16) ^ rx;

  bf16x8 aR[4][2], bR[4][2];

  for (int t = 0; t < NT; ++t) {
    const char* bufA = smem + (t & 1) * 65536;
    const char* bufB = bufA + 32768;
    const bool more = (t + 1) < NT;

    asm volatile("s_waitcnt vmcnt(0)" ::: "memory");
    __builtin_amdgcn_s_barrier();

    // ---- ph0 ----
#pragma unroll
    for (int mf = 0; mf < 4; ++mf) {
      aR[mf][0] = *(const bf16x8*)(bufA + aRow0 + mf * 2048 + col0);
      aR[mf][1] = *(const bf16x8*)(bufA + aRow0 + mf * 2048 + col1);
    }
#pragma unroll
    for (int nf = 0; nf < 2; ++nf) {
      bR[nf][0] = *(const bf16x8*)(bufB + bRow0 + nf * 2048 + col0);
      bR[nf][1] = *(const bf16x8*)(bufB + bRow0 + nf * 2048 + col1);
    }
    if (more) STAGEB4(t + 1);
    asm volatile("s_waitcnt lgkmcnt(8)" ::: "memory");
    __builtin_amdgcn_s_barrier();
    asm volatile("s_waitcnt lgkmcnt(0)" ::: "memory");
    __builtin_amdgcn_sched_barrier(0);
    __builtin_amdgcn_s_setprio(1);
#pragma unroll
    for (int mf = 0; mf < 4; ++mf)
#pragma unroll
      for (int nf = 0; nf < 2; ++nf) {
        acc[mf][nf] = mfma16(aR[mf][0], bR[nf][0], acc[mf][nf]);
        acc[mf][nf] = mfma16(aR[mf][1], bR[nf][1], acc[mf][nf]);
      }
    __builtin_amdgcn_s_setprio(0);
    __builtin_amdgcn_s_barrier();

    // ---- ph1 ----
#pragma unroll
    for (int nf = 2; nf < 4; ++nf) {
      bR[nf][0] = *(const bf16x8*)(bufB + bRow0 + nf * 2048 + col0);
      bR[nf][1] = *(const bf16x8*)(bufB + bRow0 + nf * 2048 + col1);
    }
    if (more) STAGEA4(t + 1);
    __builtin_amdgcn_s_barrier();
    asm volatile("s_waitcnt lgkmcnt(0)" ::: "memory");
    __builtin_amdgcn_sched_barrier(0);
    __builtin_amdgcn_s_setprio(1);
#pragma unroll
    for (int mf = 0; mf < 4; ++mf)
#pragma unroll
      for (int nf = 2; nf < 4; ++nf) {
        acc[mf][nf] = mfma16(aR[mf][0], bR[nf][0], acc[mf][nf]);
        acc[mf][nf] = mfma16(aR[mf][1], bR[nf][1], acc[mf][nf]);
      }
    __builtin_amdgcn_s_setprio(0);
    __builtin_amdgcn_s_barrier();

    // ---- ph2 ----
#pragma unroll
    for (int mf = 0; mf < 4; ++mf) {
      aR[mf][0] = *(const bf16x8*)(bufA + aRow0 + (4 + mf) * 2048 + col0);
      aR[mf][1] = *(const bf16x8*)(bufA + aRow0 + (4 + mf) * 2048 + col1);
    }
    __builtin_amdgcn_s_barrier();
    asm volatile("s_waitcnt lgkmcnt(0)" ::: "memory");
    __builtin_amdgcn_sched_barrier(0);
    __builtin_amdgcn_s_setprio(1);
#pragma unroll
    for (int mf = 0; mf < 4; ++mf)
#pragma unroll
      for (int nf = 0; nf < 2; ++nf) {
        acc[4 + mf][nf] = mfma16(aR[mf][0], bR[nf][0], acc[4 + mf][nf]);
        acc[4 + mf][nf] = mfma16(aR[mf][1], bR[nf][1], acc[4 + mf][nf]);
      }
    __builtin_amdgcn_s_setprio(0);
    __builtin_amdgcn_s_barrier();

    // ---- ph3 ----
    __builtin_amdgcn_s_setprio(1);
#pragma unroll
    for (int mf = 0; mf < 4; ++mf)
#pragma unroll
      for (int nf = 2; nf < 4; ++nf) {
        acc[4 + mf][nf] = mfma16(aR[mf][0], bR[nf][0], acc[4 + mf][nf]);
        acc[4 + mf][nf] = mfma16(aR[mf][1], bR[nf][1], acc[4 + mf][nf]);
      }
    __builtin_amdgcn_s_setprio(0);
  }
#undef STAGEA4
#undef STAGEB4

  const float cscale = (bn < sbl) ? QSCALE : 1.0f;
#pragma unroll
  for (int mf = 0; mf < 8; ++mf)
#pragma unroll
    for (int nf = 0; nf < 4; ++nf)
#pragma unroll
      for (int r = 0; r < 4; ++r) {
        int rowc = bm * 256 + wr * 128 + mf * 16 + lg * 4 + r;
        int colc = bn * 256 + wc * 64 + nf * 16 + lr;
        float v = acc[mf][nf][r] * cscale;
        if constexpr (sizeof(OutT) == 2)
          C[(size_t)rowc * N + colc] = (OutT)f2b(v);
        else
          C[(size_t)rowc * N + colc] = v;
      }
}

// ---------------------------------------------------------------------------
// RoPE on K and V read from fused XQKV (row stride 6144; K col 4096+, V 5120+).
__global__ __launch_bounds__(256) void rope_kv(
    const unsigned short* __restrict__ XQKV,
    const float* __restrict__ fc, const float* __restrict__ fs,
    unsigned short* __restrict__ Kr, unsigned short* __restrict__ Vt) {
  __shared__ unsigned short Vl[128][66];
  const int t = threadIdx.x;
  const int bid = blockIdx.x;  // bkv*32 + stile
  const int stile = bid & 31, bkv = bid >> 5;
  const int b = bkv >> 3, kvh = bkv & 7;
  const int s0 = stile * 64;
  const int l = t & 63;
  const int jrow = t >> 6;

  for (int j = 0; j < 16; ++j) {
    int s = s0 + j * 4 + jrow;
    ushort2 v = *(const ushort2*)(XQKV + (size_t)(b * 2048 + s) * 6144 + 4096 +
                                  kvh * 128 + 2 * l);
    float c = fc[s * 64 + l], sn = fs[s * 64 + l];
    float xr = b2f(v.x), xi = b2f(v.y);
    ushort2 o;
    o.x = f2b(xr * c - xi * sn);
    o.y = f2b(xr * sn + xi * c);
    *(ushort2*)(Kr + ((size_t)bkv * 2048 + s) * 128 + 2 * l) = o;
  }
  for (int j = 0; j < 16; ++j) {
    int ss = j * 4 + jrow;
    int s = s0 + ss;
    ushort2 v = *(const ushort2*)(XQKV + (size_t)(b * 2048 + s) * 6144 + 5120 +
                                  kvh * 128 + 2 * l);
    float c = fc[s * 64 + l], sn = fs[s * 64 + l];
    float xr = b2f(v.x), xi = b2f(v.y);
    Vl[2 * l][ss] = f2b(xr * c - xi * sn);
    Vl[2 * l + 1][ss] = f2b(xr * sn + xi * c);
  }
  __syncthreads();
  const int d = t >> 1, half = t & 1;
  unsigned short* vdst = Vt + ((size_t)bkv * 128 + d) * 2048 + s0 + half * 32;
#pragma unroll
  for (int e = 0; e < 32; e += 4) {
    ushort4 pk;
    pk.x = Vl[d][half * 32 + e];
    pk.y = Vl[d][half * 32 + e + 1];
    pk.z = Vl[d][half * 32 + e + 2];
    pk.w = Vl[d][half * 32 + e + 3];
    *(ushort4*)(vdst + e) = pk;
  }
}

// ---------------------------------------------------------------------------
// Flash attention, round 10. Grid 512 = bh(64) x qt(8); 4 waves x 64 q-rows.
// KVBLK=32, double-buffered. Chunk-major LDS (r5-verified bijections):
//   K: [16 dchunk][32 k][8]  8KB x2      V: [4 kchunk][128 d][8]  8KB x2
//   P: per-wave [4 kc][64 q][8]  4KB x4
// Total 49152B -> 2 blocks/CU (grid 512 = exact fill). K/V frags reused x4.
__global__ __launch_bounds__(256, 2) void attn_fwd(
    const unsigned short* __restrict__ XQ, const unsigned short* __restrict__ Kr,
    const unsigned short* __restrict__ Vt, unsigned short* __restrict__ AO) {
  extern __shared__ char smem[];  // 49152
  char* Ksm = smem;                                      // [2][8192]
  char* Vsm = smem + 16384;                              // [2][8192]
  unsigned short* Ps = (unsigned short*)(smem + 32768);  // [4][4][64][8]
  const int t = threadIdx.x;
  const int lane = t & 63, w = t >> 6;
  const int lr = lane & 15, lg = lane >> 4;

  const int bid = blockIdx.x;
  const int nwg = gridDim.x;  // 512
  const int swz = (bid & 7) * (nwg >> 3) + (bid >> 3);
  const int qt = swz & 7;
  const int bh = swz >> 3;
  const int b = bh >> 5, h = bh & 31;
  const int bkv = b * 8 + (h >> 2);

  // Q fragments: 64 q-rows (4 x 16), full D=128 in regs (64 VGPR)
  bf16x8 qf[4][4];
#pragma unroll
  for (int q4 = 0; q4 < 4; ++q4) {
    const unsigned short* qp =
        XQ + ((size_t)(b * 2048 + qt * 256 + w * 64 + q4 * 16 + lr)) * 6144 +
        h * 128 + lg * 8;
#pragma unroll
    for (int dc = 0; dc < 4; ++dc) qf[q4][dc] = *(const bf16x8*)(qp + dc * 32);
  }

  f32x4 acc[4][8];
#pragma unroll
  for (int q4 = 0; q4 < 4; ++q4)
#pragma unroll
    for (int i = 0; i < 8; ++i) acc[q4][i] = (f32x4){0.f, 0.f, 0.f, 0.f};
  float l_[4][4];
#pragma unroll
  for (int q4 = 0; q4 < 4; ++q4)
#pragma unroll
    for (int r = 0; r < 4; ++r) l_[q4][r] = 0.f;

  const unsigned short* Kbase = Kr + (size_t)bkv * 2048 * 128;
  const unsigned short* Vbase = Vt + (size_t)bkv * 128 * 2048;

  // staging: 512 chunks of 16B per operand per tile; c0=t, c1=t+256
  const int c0 = t, c1 = t + 256;
  const int kK0 = c0 & 31, dC0 = c0 >> 5;
  const int kK1 = c1 & 31, dC1 = c1 >> 5;
  const int vD0 = c0 & 127, vKc0 = c0 >> 7;
  const int vD1 = c1 & 127, vKc1 = c1 >> 7;
  const int dstb0 = (c0 & ~63) * 16;
  const int dstb1 = (c1 & ~63) * 16;

#define STAGE_KV(bufi, kt)                                                     \
  {                                                                            \
    char* kd = Ksm + (bufi)*8192;                                              \
    char* vd = Vsm + (bufi)*8192;                                              \
    load16(Kbase + (size_t)((kt)*32 + kK0) * 128 + dC0 * 8, kd + dstb0);       \
    load16(Kbase + (size_t)((kt)*32 + kK1) * 128 + dC1 * 8, kd + dstb1);       \
    load16(Vbase + (size_t)vD0 * 2048 + (kt)*32 + vKc0 * 8, vd + dstb0);       \
    load16(Vbase + (size_t)vD1 * 2048 + (kt)*32 + vKc1 * 8, vd + dstb1);       \
  }

  STAGE_KV(0, 0);
  asm volatile("s_waitcnt vmcnt(0)" ::: "memory");
  __builtin_amdgcn_s_barrier();

  unsigned short* Pw = Ps + w * 2048;              // [4 kc][64 q][8]
  const int pbase = (lr >> 3) * 512 + (lr & 7);    // halfword offset

  for (int kt = 0; kt < 64; ++kt) {
    const int cur = kt & 1;
    if (kt < 63) STAGE_KV(cur ^ 1, kt + 1);

    const char* Kc = Ksm + cur * 8192;
    const char* Vc = Vsm + cur * 8192;

    // QK^T + exp2 + P-store (nf = 0..1 chunks of 16 k); kf reused x4 q-frags
#pragma unroll
    for (int nf = 0; nf < 2; ++nf) {
      f32x4 s[4];
#pragma unroll
      for (int q4 = 0; q4 < 4; ++q4) s[q4] = (f32x4){0.f, 0.f, 0.f, 0.f};
#pragma unroll
      for (int dc = 0; dc < 4; ++dc) {
        bf16x8 kf =
            *(const bf16x8*)(Kc + ((dc * 4 + lg) * 32 + nf * 16 + lr) * 16);
#pragma unroll
        for (int q4 = 0; q4 < 4; ++q4) s[q4] = mfma16(qf[q4][dc], kf, s[q4]);
      }
      const int pb = pbase + nf * 1024;  // kc = nf*2 + (lr>>3)
#pragma unroll
      for (int q4 = 0; q4 < 4; ++q4)
#pragma unroll
        for (int r = 0; r < 4; ++r) {
          float p = __builtin_amdgcn_exp2f(s[q4][r]);
          l_[q4][r] += p;
          Pw[pb + (q4 * 16 + lg * 4 + r) * 8] = f2b_fast(p);
        }
    }

    // PV: vf reused x4 q-frags; kc = lg
    bf16x8 pf[4];
#pragma unroll
    for (int q4 = 0; q4 < 4; ++q4)
      pf[q4] = *(const bf16x8*)(Pw + lg * 512 + (q4 * 16 + lr) * 8);
#pragma unroll
    for (int dt = 0; dt < 8; ++dt) {
      bf16x8 vf = *(const bf16x8*)(Vc + (lg * 128 + dt * 16 + lr) * 16);
#pragma unroll
      for (int q4 = 0; q4 < 4; ++q4)
        acc[q4][dt] = mfma16(pf[q4], vf, acc[q4][dt]);
    }

    asm volatile("s_waitcnt vmcnt(0)" ::: "memory");
    __builtin_amdgcn_s_barrier();
  }
#undef STAGE_KV

  // reduce l across the 16 lanes of each lg row-group
#pragma unroll
  for (int q4 = 0; q4 < 4; ++q4)
#pragma unroll
    for (int r = 0; r < 4; ++r) {
#pragma unroll
      for (int o = 1; o < 16; o <<= 1) l_[q4][r] += __shfl_xor(l_[q4][r], o);
    }

#pragma unroll
  for (int q4 = 0; q4 < 4; ++q4)
#pragma unroll
    for (int r = 0; r < 4; ++r) {
      float inv = 1.f / l_[q4][r];
      size_t rowb =
          ((size_t)(b * 2048 + qt * 256 + w * 64 + q4 * 16 + lg * 4 + r)) * 4096 +
          h * 128;
#pragma unroll
      for (int dt = 0; dt < 8; ++dt)
        AO[rowb + dt * 16 + lr] = f2b_fast(acc[q4][dt][r] * inv);
    }
}

// ---------------------------------------------------------------------------
extern "C" void kernel_launch(void* const* d_in, const int* in_sizes, int n_in,
                              void* d_out, int out_size, void* d_ws, size_t ws_size,
                              hipStream_t stream) {
  const float* x  = (const float*)d_in[0];
  const float* fc = (const float*)d_in[2];
  const float* fs = (const float*)d_in[3];
  const float* wq = (const float*)d_in[4];
  const float* wk = (const float*)d_in[5];
  const float* wv = (const float*)d_in[6];
  const float* wo = (const float*)d_in[7];

  const size_t MB = 1024ull * 1024ull;
  char* ws = (char*)d_ws;
  unsigned short* Xb   = (unsigned short*)(ws);           // 32MB, dead after QKV gemm
  unsigned short* Wsc  = (unsigned short*)(ws + 32 * MB); // 48MB (wq|wk|wv), later wo
  unsigned short* Kr   = (unsigned short*)(ws);           // [0,8) reuse Xb
  unsigned short* Vt   = (unsigned short*)(ws + 8 * MB);  // [8,16)
  unsigned short* AO   = (unsigned short*)(ws + 80 * MB); // 32MB
  unsigned short* XQKV = (unsigned short*)d_out;          // 48MB of 64MB d_out

  (void)hipFuncSetAttribute((const void*)gemm256<unsigned short>,
                            hipFuncAttributeMaxDynamicSharedMemorySize, 131072);
  (void)hipFuncSetAttribute((const void*)gemm256<float>,
                            hipFuncAttributeMaxDynamicSharedMemorySize, 131072);
  (void)hipFuncSetAttribute((const void*)attn_fwd,
                            hipFuncAttributeMaxDynamicSharedMemorySize, 49152);

  dim3 blk(256);
  dim3 blk512(512);
  cvt_f32_bf16<<<2048, blk, 0, stream>>>(x, Xb, (2 * 2048 * 4096) / 4);
  cvt_f32_bf16<<<2048, blk, 0, stream>>>(wq, Wsc, (4096 * 4096) / 4);
  cvt_f32_bf16<<<2048, blk, 0, stream>>>(wk, Wsc + 4096 * 4096, (1024 * 4096) / 4);
  cvt_f32_bf16<<<2048, blk, 0, stream>>>(wv, Wsc + 5120 * 4096, (1024 * 4096) / 4);
  gemm256<unsigned short><<<384, blk512, 131072, stream>>>(
      Xb, Wsc, XQKV, 4096, 6144, 4096, /*sbl=*/16);
  rope_kv<<<512, blk, 0, stream>>>(XQKV, fc, fs, Kr, Vt);
  attn_fwd<<<512, blk, 49152, stream>>>(XQKV, Kr, Vt, AO);
  cvt_f32_bf16<<<2048, blk, 0, stream>>>(wo, Wsc, (4096 * 4096) / 4);
  gemm256<float><<<256, blk512, 131072, stream>>>(
      AO, Wsc, (float*)d_out, 4096, 4096, 4096, /*sbl=*/0);
}

// Round 11
// 542.935 us; speedup vs baseline: 1.2944x; 1.0401x over previous
//
#include <hip/hip_runtime.h>
#include <hip/hip_bf16.h>

// ---------------------------------------------------------------------------
// SelfAttention (B=2,S=2048,D=4096, NH=32,NKV=8,HD=128, NREP=4, non-causal)
// RoPE on K and V (reference quirk), NOT on Q.
// Round 11: gemm256 -> m201-style 8-phase counted-vmcnt schedule:
//   2 K-tiles/iteration (dbuf0/dbuf1), half-tile staging (2 loads/phase),
//   stage stream ph1:A1(T1) ph2:A0(Te) ph3:B0(Te) ph4:B1(Te) ph5:A1(Te)
//   ph6:A0(To) ph7:B0(To) ph8:B1(To); uniform vmcnt(10)+barrier gates at
//   read-phases (issue->use distance >= 6 phases); B rows LDS-permuted so
//   halves align with nf-phases; wrap-staging keeps the stream uniform at
//   the last iteration. Attn/rope/cvt unchanged from round 10.
// ---------------------------------------------------------------------------

typedef short bf16x8 __attribute__((ext_vector_type(8)));
typedef float f32x4 __attribute__((ext_vector_type(4)));

__device__ __forceinline__ void load16(const void* g, void* l) {
  __builtin_amdgcn_global_load_lds(
      (const __attribute__((address_space(1))) void*)g,
      (__attribute__((address_space(3))) void*)l, 16, 0, 0);
}

__device__ __forceinline__ f32x4 mfma16(bf16x8 a, bf16x8 b, f32x4 c) {
  return __builtin_amdgcn_mfma_f32_16x16x32_bf16(a, b, c, 0, 0, 0);
}

__device__ __forceinline__ unsigned short f2b(float f) {
  union { float f; unsigned int u; } v; v.f = f;
  unsigned int u = v.u;
  return (unsigned short)((u + 0x7fffu + ((u >> 16) & 1u)) >> 16);
}
__device__ __forceinline__ float b2f(unsigned short u) {
  union { unsigned int u; float f; } v; v.u = ((unsigned int)u) << 16;
  return v.f;
}
__device__ __forceinline__ unsigned short f2b_fast(float f) {
  __hip_bfloat16 h = __float2bfloat16(f);
  return *reinterpret_cast<unsigned short*>(&h);
}

#define QSCALE (0.08838834764831845f * 1.4426950408889634f)

// ---------------------------------------------------------------------------
__global__ __launch_bounds__(256) void cvt_f32_bf16(
    const float* __restrict__ in, unsigned short* __restrict__ out, int n4) {
  int idx = blockIdx.x * 256 + threadIdx.x;
  int stride = gridDim.x * 256;
  for (int i = idx; i < n4; i += stride) {
    float4 v = reinterpret_cast<const float4*>(in)[i];
    ushort4 o;
    o.x = f2b(v.x); o.y = f2b(v.y); o.z = f2b(v.z); o.w = f2b(v.w);
    reinterpret_cast<ushort4*>(out)[i] = o;
  }
}

// ---------------------------------------------------------------------------
// 256x256 tile, BK=64, 8 waves (2Mx4N), per-wave 128x64 output.
// LDS: dbuf0 @0 (A 32K | B 32K), dbuf1 @64K. Row-major rows of 64 halfwords,
// k-slot XOR swizzle by (row&7) (r8-verified: 0 bank conflicts).
// B rows permuted: logical row (wc*64+nf*16+lr) stored at
// prow = (nf>>1)*128 + wc*32 + (nf&1)*16 + lr  -> B-half h = loads {2h,2h+1}.
// A-half h = loads {h, h+2} (rows 64j..64j+63 per load j).
template <typename OutT>
__global__ __launch_bounds__(512, 2) void gemm256(
    const unsigned short* __restrict__ A, const unsigned short* __restrict__ Bw,
    OutT* __restrict__ C, int M, int N, int K, int sbl) {
  extern __shared__ char smem[];  // 131072
  const int tid = threadIdx.x;
  const int lane = tid & 63;
  const int w = tid >> 6;
  const int lr = lane & 15, lg = lane >> 4;
  const int wr = w >> 2, wc = w & 3;

  const int nbn = N >> 8;
  const int bid = blockIdx.x, nwg = gridDim.x;
  const int swz = (bid & 7) * (nwg >> 3) + (bid >> 3);  // nwg % 8 == 0
  const int bm = swz / nbn, bn = swz % nbn;

  const unsigned short* Ag = A + (size_t)bm * 256 * K;
  const unsigned short* Bg = Bw + (size_t)bn * 256 * K;

  // staging: chunk c = tid + j*512 (16B each); u = c>>3 is LDS row index.
  // A source row = u; B source row = brow(u) (inverse of prow permutation).
  int aoffs[4], boffs[4], sdst[4];
#pragma unroll
  for (int j = 0; j < 4; ++j) {
    const int c = tid + j * 512;
    const int u = c >> 3;
    const int slot = ((c & 7) ^ (u & 7)) << 3;
    aoffs[j] = u * K + slot;
    const int br = ((u & 127) >> 5) * 64 + (u >> 7) * 32 + (u & 31);
    boffs[j] = br * K + slot;
    sdst[j] = ((tid & ~63) << 4) + j * 8192;
  }

#define ST_A(hh, tt)                                                          \
  {                                                                           \
    char* d = smem + (((tt)&1) * 65536);                                      \
    load16(Ag + aoffs[(hh)] + ((tt) << 6), d + sdst[(hh)]);                   \
    load16(Ag + aoffs[(hh) + 2] + ((tt) << 6), d + sdst[(hh) + 2]);           \
  }
#define ST_B(hh, tt)                                                          \
  {                                                                           \
    char* d = smem + (((tt)&1) * 65536) + 32768;                              \
    load16(Bg + boffs[(hh)*2] + ((tt) << 6), d + sdst[(hh)*2]);               \
    load16(Bg + boffs[(hh)*2 + 1] + ((tt) << 6), d + sdst[(hh)*2 + 1]);       \
  }
#define GATE10                                                                \
  asm volatile("s_waitcnt vmcnt(10)" ::: "memory");                           \
  __builtin_amdgcn_s_barrier();
#define LGKM0                                                                 \
  asm volatile("s_waitcnt lgkmcnt(0)" ::: "memory");                          \
  __builtin_amdgcn_sched_barrier(0);

  f32x4 acc[8][4];
#pragma unroll
  for (int m = 0; m < 8; ++m)
#pragma unroll
    for (int n = 0; n < 4; ++n) acc[m][n] = (f32x4){0.f, 0.f, 0.f, 0.f};

  // prologue: 7 halves in stream order (virtual prev-iteration ph2..ph8)
  ST_A(0, 0); ST_B(0, 0); ST_B(1, 0); ST_A(1, 0);
  ST_A(0, 1); ST_B(0, 1); ST_B(1, 1);

  const int NT = K >> 6;       // 64
  const int NI = NT >> 1;      // 32
  const int xr = (lr & 7) << 4;
  const int aBase = (wr * 128 + lr) * 128;   // + mf*2048 + col
  const int bBase = (wc * 32 + lr) * 128;    // + (nf&1)*2048 (+16384 if nf>=2)
  const int col0 = (lg * 16) ^ xr;
  const int col1 = (64 + lg * 16) ^ xr;

  bf16x8 aR[4][2], b01[2][2], b23[2][2];

  for (int i = 0; i < NI; ++i) {
    const int T1 = 2 * i + 1;
    const int te = (2 * i + 2 < NT) ? 2 * i + 2 : 0;  // wrap keeps stream uniform
    const int to = (2 * i + 3 < NT) ? 2 * i + 3 : 1;
    const char* d0 = smem;
    const char* d1 = smem + 65536;

    // ---- ph1: T0 mf0-3 x nf0-1 ----
    GATE10;
#pragma unroll
    for (int mf = 0; mf < 4; ++mf) {
      aR[mf][0] = *(const bf16x8*)(d0 + aBase + mf * 2048 + col0);
      aR[mf][1] = *(const bf16x8*)(d0 + aBase + mf * 2048 + col1);
    }
#pragma unroll
    for (int nf = 0; nf < 2; ++nf) {
      b01[nf][0] = *(const bf16x8*)(d0 + 32768 + bBase + nf * 2048 + col0);
      b01[nf][1] = *(const bf16x8*)(d0 + 32768 + bBase + nf * 2048 + col1);
    }
    ST_A(1, T1);
    LGKM0;
    __builtin_amdgcn_s_setprio(1);
#pragma unroll
    for (int mf = 0; mf < 4; ++mf)
#pragma unroll
      for (int nf = 0; nf < 2; ++nf) {
        acc[mf][nf] = mfma16(aR[mf][0], b01[nf][0], acc[mf][nf]);
        acc[mf][nf] = mfma16(aR[mf][1], b01[nf][1], acc[mf][nf]);
      }
    __builtin_amdgcn_s_setprio(0);

    // ---- ph2: T0 mf0-3 x nf2-3 ----
    GATE10;
#pragma unroll
    for (int nf = 0; nf < 2; ++nf) {
      b23[nf][0] = *(const bf16x8*)(d0 + 32768 + 16384 + bBase + nf * 2048 + col0);
      b23[nf][1] = *(const bf16x8*)(d0 + 32768 + 16384 + bBase + nf * 2048 + col1);
    }
    ST_A(0, te);
    LGKM0;
    __builtin_amdgcn_s_setprio(1);
#pragma unroll
    for (int mf = 0; mf < 4; ++mf)
#pragma unroll
      for (int nf = 0; nf < 2; ++nf) {
        acc[mf][2 + nf] = mfma16(aR[mf][0], b23[nf][0], acc[mf][2 + nf]);
        acc[mf][2 + nf] = mfma16(aR[mf][1], b23[nf][1], acc[mf][2 + nf]);
      }
    __builtin_amdgcn_s_setprio(0);

    // ---- ph3: T0 mf4-7 x nf0-1 ----
    GATE10;
#pragma unroll
    for (int mf = 0; mf < 4; ++mf) {
      aR[mf][0] = *(const bf16x8*)(d0 + aBase + (4 + mf) * 2048 + col0);
      aR[mf][1] = *(const bf16x8*)(d0 + aBase + (4 + mf) * 2048 + col1);
    }
    ST_B(0, te);
    LGKM0;
    __builtin_amdgcn_s_setprio(1);
#pragma unroll
    for (int mf = 0; mf < 4; ++mf)
#pragma unroll
      for (int nf = 0; nf < 2; ++nf) {
        acc[4 + mf][nf] = mfma16(aR[mf][0], b01[nf][0], acc[4 + mf][nf]);
        acc[4 + mf][nf] = mfma16(aR[mf][1], b01[nf][1], acc[4 + mf][nf]);
      }
    __builtin_amdgcn_s_setprio(0);

    // ---- ph4: T0 mf4-7 x nf2-3 (no reads, no gate) ----
    ST_B(1, te);
    __builtin_amdgcn_s_setprio(1);
#pragma unroll
    for (int mf = 0; mf < 4; ++mf)
#pragma unroll
      for (int nf = 0; nf < 2; ++nf) {
        acc[4 + mf][2 + nf] = mfma16(aR[mf][0], b23[nf][0], acc[4 + mf][2 + nf]);
        acc[4 + mf][2 + nf] = mfma16(aR[mf][1], b23[nf][1], acc[4 + mf][2 + nf]);
      }
    __builtin_amdgcn_s_setprio(0);

    // ---- ph5: T1 mf0-3 x nf0-1 ----
    GATE10;
#pragma unroll
    for (int mf = 0; mf < 4; ++mf) {
      aR[mf][0] = *(const bf16x8*)(d1 + aBase + mf * 2048 + col0);
      aR[mf][1] = *(const bf16x8*)(d1 + aBase + mf * 2048 + col1);
    }
#pragma unroll
    for (int nf = 0; nf < 2; ++nf) {
      b01[nf][0] = *(const bf16x8*)(d1 + 32768 + bBase + nf * 2048 + col0);
      b01[nf][1] = *(const bf16x8*)(d1 + 32768 + bBase + nf * 2048 + col1);
    }
    ST_A(1, te);
    LGKM0;
    __builtin_amdgcn_s_setprio(1);
#pragma unroll
    for (int mf = 0; mf < 4; ++mf)
#pragma unroll
      for (int nf = 0; nf < 2; ++nf) {
        acc[mf][nf] = mfma16(aR[mf][0], b01[nf][0], acc[mf][nf]);
        acc[mf][nf] = mfma16(aR[mf][1], b01[nf][1], acc[mf][nf]);
      }
    __builtin_amdgcn_s_setprio(0);

    // ---- ph6: T1 mf0-3 x nf2-3 ----
    GATE10;
#pragma unroll
    for (int nf = 0; nf < 2; ++nf) {
      b23[nf][0] = *(const bf16x8*)(d1 + 32768 + 16384 + bBase + nf * 2048 + col0);
      b23[nf][1] = *(const bf16x8*)(d1 + 32768 + 16384 + bBase + nf * 2048 + col1);
    }
    ST_A(0, to);
    LGKM0;
    __builtin_amdgcn_s_setprio(1);
#pragma unroll
    for (int mf = 0; mf < 4; ++mf)
#pragma unroll
      for (int nf = 0; nf < 2; ++nf) {
        acc[mf][2 + nf] = mfma16(aR[mf][0], b23[nf][0], acc[mf][2 + nf]);
        acc[mf][2 + nf] = mfma16(aR[mf][1], b23[nf][1], acc[mf][2 + nf]);
      }
    __builtin_amdgcn_s_setprio(0);

    // ---- ph7: T1 mf4-7 x nf0-1 ----
    GATE10;
#pragma unroll
    for (int mf = 0; mf < 4; ++mf) {
      aR[mf][0] = *(const bf16x8*)(d1 + aBase + (4 + mf) * 2048 + col0);
      aR[mf][1] = *(const bf16x8*)(d1 + aBase + (4 + mf) * 2048 + col1);
    }
    ST_B(0, to);
    LGKM0;
    __builtin_amdgcn_s_setprio(1);
#pragma unroll
    for (int mf = 0; mf < 4; ++mf)
#pragma unroll
      for (int nf = 0; nf < 2; ++nf) {
        acc[4 + mf][nf] = mfma16(aR[mf][0], b01[nf][0], acc[4 + mf][nf]);
        acc[4 + mf][nf] = mfma16(aR[mf][1], b01[nf][1], acc[4 + mf][nf]);
      }
    __builtin_amdgcn_s_setprio(0);

    // ---- ph8: T1 mf4-7 x nf2-3 (no reads, no gate) ----
    ST_B(1, to);
    __builtin_amdgcn_s_setprio(1);
#pragma unroll
    for (int mf = 0; mf < 4; ++mf)
#pragma unroll
      for (int nf = 0; nf < 2; ++nf) {
        acc[4 + mf][2 + nf] = mfma16(aR[mf][0], b23[nf][0], acc[4 + mf][2 + nf]);
        acc[4 + mf][2 + nf] = mfma16(aR[mf][1], b23[nf][1], acc[4 + mf][2 + nf]);
      }
    __builtin_amdgcn_s_setprio(0);
  }
#undef ST_A
#undef ST_B
#undef GATE10
#undef LGKM0

  const float cscale = (bn < sbl) ? QSCALE : 1.0f;
#pragma unroll
  for (int mf = 0; mf < 8; ++mf)
#pragma unroll
    for (int nf = 0; nf < 4; ++nf)
#pragma unroll
      for (int r = 0; r < 4; ++r) {
        int rowc = bm * 256 + wr * 128 + mf * 16 + lg * 4 + r;
        int colc = bn * 256 + wc * 64 + nf * 16 + lr;
        float v = acc[mf][nf][r] * cscale;
        if constexpr (sizeof(OutT) == 2)
          C[(size_t)rowc * N + colc] = (OutT)f2b(v);
        else
          C[(size_t)rowc * N + colc] = v;
      }
}

// ---------------------------------------------------------------------------
// RoPE on K and V read from fused XQKV (row stride 6144; K col 4096+, V 5120+).
__global__ __launch_bounds__(256) void rope_kv(
    const unsigned short* __restrict__ XQKV,
    const float* __restrict__ fc, const float* __restrict__ fs,
    unsigned short* __restrict__ Kr, unsigned short* __restrict__ Vt) {
  __shared__ unsigned short Vl[128][66];
  const int t = threadIdx.x;
  const int bid = blockIdx.x;  // bkv*32 + stile
  const int stile = bid & 31, bkv = bid >> 5;
  const int b = bkv >> 3, kvh = bkv & 7;
  const int s0 = stile * 64;
  const int l = t & 63;
  const int jrow = t >> 6;

  for (int j = 0; j < 16; ++j) {
    int s = s0 + j * 4 + jrow;
    ushort2 v = *(const ushort2*)(XQKV + (size_t)(b * 2048 + s) * 6144 + 4096 +
                                  kvh * 128 + 2 * l);
    float c = fc[s * 64 + l], sn = fs[s * 64 + l];
    float xr = b2f(v.x), xi = b2f(v.y);
    ushort2 o;
    o.x = f2b(xr * c - xi * sn);
    o.y = f2b(xr * sn + xi * c);
    *(ushort2*)(Kr + ((size_t)bkv * 2048 + s) * 128 + 2 * l) = o;
  }
  for (int j = 0; j < 16; ++j) {
    int ss = j * 4 + jrow;
    int s = s0 + ss;
    ushort2 v = *(const ushort2*)(XQKV + (size_t)(b * 2048 + s) * 6144 + 5120 +
                                  kvh * 128 + 2 * l);
    float c = fc[s * 64 + l], sn = fs[s * 64 + l];
    float xr = b2f(v.x), xi = b2f(v.y);
    Vl[2 * l][ss] = f2b(xr * c - xi * sn);
    Vl[2 * l + 1][ss] = f2b(xr * sn + xi * c);
  }
  __syncthreads();
  const int d = t >> 1, half = t & 1;
  unsigned short* vdst = Vt + ((size_t)bkv * 128 + d) * 2048 + s0 + half * 32;
#pragma unroll
  for (int e = 0; e < 32; e += 4) {
    ushort4 pk;
    pk.x = Vl[d][half * 32 + e];
    pk.y = Vl[d][half * 32 + e + 1];
    pk.z = Vl[d][half * 32 + e + 2];
    pk.w = Vl[d][half * 32 + e + 3];
    *(ushort4*)(vdst + e) = pk;
  }
}

// ---------------------------------------------------------------------------
// Flash attention (round-10 kernel, unchanged). Grid 512; 4 waves x 64 q-rows.
__global__ __launch_bounds__(256, 2) void attn_fwd(
    const unsigned short* __restrict__ XQ, const unsigned short* __restrict__ Kr,
    const unsigned short* __restrict__ Vt, unsigned short* __restrict__ AO) {
  extern __shared__ char smem[];  // 49152
  char* Ksm = smem;                                      // [2][8192]
  char* Vsm = smem + 16384;                              // [2][8192]
  unsigned short* Ps = (unsigned short*)(smem + 32768);  // [4][4][64][8]
  const int t = threadIdx.x;
  const int lane = t & 63, w = t >> 6;
  const int lr = lane & 15, lg = lane >> 4;

  const int bid = blockIdx.x;
  const int nwg = gridDim.x;  // 512
  const int swz = (bid & 7) * (nwg >> 3) + (bid >> 3);
  const int qt = swz & 7;
  const int bh = swz >> 3;
  const int b = bh >> 5, h = bh & 31;
  const int bkv = b * 8 + (h >> 2);

  bf16x8 qf[4][4];
#pragma unroll
  for (int q4 = 0; q4 < 4; ++q4) {
    const unsigned short* qp =
        XQ + ((size_t)(b * 2048 + qt * 256 + w * 64 + q4 * 16 + lr)) * 6144 +
        h * 128 + lg * 8;
#pragma unroll
    for (int dc = 0; dc < 4; ++dc) qf[q4][dc] = *(const bf16x8*)(qp + dc * 32);
  }

  f32x4 acc[4][8];
#pragma unroll
  for (int q4 = 0; q4 < 4; ++q4)
#pragma unroll
    for (int i = 0; i < 8; ++i) acc[q4][i] = (f32x4){0.f, 0.f, 0.f, 0.f};
  float l_[4][4];
#pragma unroll
  for (int q4 = 0; q4 < 4; ++q4)
#pragma unroll
    for (int r = 0; r < 4; ++r) l_[q4][r] = 0.f;

  const unsigned short* Kbase = Kr + (size_t)bkv * 2048 * 128;
  const unsigned short* Vbase = Vt + (size_t)bkv * 128 * 2048;

  const int c0 = t, c1 = t + 256;
  const int kK0 = c0 & 31, dC0 = c0 >> 5;
  const int kK1 = c1 & 31, dC1 = c1 >> 5;
  const int vD0 = c0 & 127, vKc0 = c0 >> 7;
  const int vD1 = c1 & 127, vKc1 = c1 >> 7;
  const int dstb0 = (c0 & ~63) * 16;
  const int dstb1 = (c1 & ~63) * 16;

#define STAGE_KV(bufi, kt)                                                     \
  {                                                                            \
    char* kd = Ksm + (bufi)*8192;                                              \
    char* vd = Vsm + (bufi)*8192;                                              \
    load16(Kbase + (size_t)((kt)*32 + kK0) * 128 + dC0 * 8, kd + dstb0);       \
    load16(Kbase + (size_t)((kt)*32 + kK1) * 128 + dC1 * 8, kd + dstb1);       \
    load16(Vbase + (size_t)vD0 * 2048 + (kt)*32 + vKc0 * 8, vd + dstb0);       \
    load16(Vbase + (size_t)vD1 * 2048 + (kt)*32 + vKc1 * 8, vd + dstb1);       \
  }

  STAGE_KV(0, 0);
  asm volatile("s_waitcnt vmcnt(0)" ::: "memory");
  __builtin_amdgcn_s_barrier();

  unsigned short* Pw = Ps + w * 2048;              // [4 kc][64 q][8]
  const int pbase = (lr >> 3) * 512 + (lr & 7);    // halfword offset

  for (int kt = 0; kt < 64; ++kt) {
    const int cur = kt & 1;
    if (kt < 63) STAGE_KV(cur ^ 1, kt + 1);

    const char* Kc = Ksm + cur * 8192;
    const char* Vc = Vsm + cur * 8192;

#pragma unroll
    for (int nf = 0; nf < 2; ++nf) {
      f32x4 s[4];
#pragma unroll
      for (int q4 = 0; q4 < 4; ++q4) s[q4] = (f32x4){0.f, 0.f, 0.f, 0.f};
#pragma unroll
      for (int dc = 0; dc < 4; ++dc) {
        bf16x8 kf =
            *(const bf16x8*)(Kc + ((dc * 4 + lg) * 32 + nf * 16 + lr) * 16);
#pragma unroll
        for (int q4 = 0; q4 < 4; ++q4) s[q4] = mfma16(qf[q4][dc], kf, s[q4]);
      }
      const int pb = pbase + nf * 1024;  // kc = nf*2 + (lr>>3)
#pragma unroll
      for (int q4 = 0; q4 < 4; ++q4)
#pragma unroll
        for (int r = 0; r < 4; ++r) {
          float p = __builtin_amdgcn_exp2f(s[q4][r]);
          l_[q4][r] += p;
          Pw[pb + (q4 * 16 + lg * 4 + r) * 8] = f2b_fast(p);
        }
    }

    bf16x8 pf[4];
#pragma unroll
    for (int q4 = 0; q4 < 4; ++q4)
      pf[q4] = *(const bf16x8*)(Pw + lg * 512 + (q4 * 16 + lr) * 8);
#pragma unroll
    for (int dt = 0; dt < 8; ++dt) {
      bf16x8 vf = *(const bf16x8*)(Vc + (lg * 128 + dt * 16 + lr) * 16);
#pragma unroll
      for (int q4 = 0; q4 < 4; ++q4)
        acc[q4][dt] = mfma16(pf[q4], vf, acc[q4][dt]);
    }

    asm volatile("s_waitcnt vmcnt(0)" ::: "memory");
    __builtin_amdgcn_s_barrier();
  }
#undef STAGE_KV

#pragma unroll
  for (int q4 = 0; q4 < 4; ++q4)
#pragma unroll
    for (int r = 0; r < 4; ++r) {
#pragma unroll
      for (int o = 1; o < 16; o <<= 1) l_[q4][r] += __shfl_xor(l_[q4][r], o);
    }

#pragma unroll
  for (int q4 = 0; q4 < 4; ++q4)
#pragma unroll
    for (int r = 0; r < 4; ++r) {
      float inv = 1.f / l_[q4][r];
      size_t rowb =
          ((size_t)(b * 2048 + qt * 256 + w * 64 + q4 * 16 + lg * 4 + r)) * 4096 +
          h * 128;
#pragma unroll
      for (int dt = 0; dt < 8; ++dt)
        AO[rowb + dt * 16 + lr] = f2b_fast(acc[q4][dt][r] * inv);
    }
}

// ---------------------------------------------------------------------------
extern "C" void kernel_launch(void* const* d_in, const int* in_sizes, int n_in,
                              void* d_out, int out_size, void* d_ws, size_t ws_size,
                              hipStream_t stream) {
  const float* x  = (const float*)d_in[0];
  const float* fc = (const float*)d_in[2];
  const float* fs = (const float*)d_in[3];
  const float* wq = (const float*)d_in[4];
  const float* wk = (const float*)d_in[5];
  const float* wv = (const float*)d_in[6];
  const float* wo = (const float*)d_in[7];

  const size_t MB = 1024ull * 1024ull;
  char* ws = (char*)d_ws;
  unsigned short* Xb   = (unsigned short*)(ws);           // 32MB, dead after QKV gemm
  unsigned short* Wsc  = (unsigned short*)(ws + 32 * MB); // 48MB (wq|wk|wv), later wo
  unsigned short* Kr   = (unsigned short*)(ws);           // [0,8) reuse Xb
  unsigned short* Vt   = (unsigned short*)(ws + 8 * MB);  // [8,16)
  unsigned short* AO   = (unsigned short*)(ws + 80 * MB); // 32MB
  unsigned short* XQKV = (unsigned short*)d_out;          // 48MB of 64MB d_out

  (void)hipFuncSetAttribute((const void*)gemm256<unsigned short>,
                            hipFuncAttributeMaxDynamicSharedMemorySize, 131072);
  (void)hipFuncSetAttribute((const void*)gemm256<float>,
                            hipFuncAttributeMaxDynamicSharedMemorySize, 131072);
  (void)hipFuncSetAttribute((const void*)attn_fwd,
                            hipFuncAttributeMaxDynamicSharedMemorySize, 49152);

  dim3 blk(256);
  dim3 blk512(512);
  cvt_f32_bf16<<<2048, blk, 0, stream>>>(x, Xb, (2 * 2048 * 4096) / 4);
  cvt_f32_bf16<<<2048, blk, 0, stream>>>(wq, Wsc, (4096 * 4096) / 4);
  cvt_f32_bf16<<<2048, blk, 0, stream>>>(wk, Wsc + 4096 * 4096, (1024 * 4096) / 4);
  cvt_f32_bf16<<<2048, blk, 0, stream>>>(wv, Wsc + 5120 * 4096, (1024 * 4096) / 4);
  gemm256<unsigned short><<<384, blk512, 131072, stream>>>(
      Xb, Wsc, XQKV, 4096, 6144, 4096, /*sbl=*/16);
  rope_kv<<<512, blk, 0, stream>>>(XQKV, fc, fs, Kr, Vt);
  attn_fwd<<<512, blk, 49152, stream>>>(XQKV, Kr, Vt, AO);
  cvt_f32_bf16<<<2048, blk, 0, stream>>>(wo, Wsc, (4096 * 4096) / 4);
  gemm256<float><<<256, blk512, 131072, stream>>>(
      AO, Wsc, (float*)d_out, 4096, 4096, 4096, /*sbl=*/0);
}